// Round 1
// baseline (303.222 us; speedup 1.0000x reference)
//
#include <hip/hip_runtime.h>
#include <hip/hip_bf16.h>

#define B_ 8
#define C_ 2048
#define E_ 1024
#define H_ 128
#define M_ (B_*C_)   // 16384 rows total

typedef __attribute__((ext_vector_type(8))) short bf16x8;
typedef __attribute__((ext_vector_type(4))) float f32x4;

__device__ __forceinline__ unsigned short f2bf(float f) {
    union { float f; unsigned int u; } v; v.f = f;
    unsigned int u = v.u;
    u += 0x7fff + ((u >> 16) & 1);   // RNE
    return (unsigned short)(u >> 16);
}

// ---------------- W transpose+convert: (E,H) f32 -> (H,E) bf16, x3 ----------
__global__ __launch_bounds__(256) void wt_kernel(const float* __restrict__ Wq,
                                                 const float* __restrict__ Wk,
                                                 const float* __restrict__ Wv,
                                                 unsigned short* __restrict__ WT) {
    int z = blockIdx.y;
    const float* W = (z == 0) ? Wq : (z == 1) ? Wk : Wv;
    unsigned short* o = WT + (size_t)z * H_ * E_;
    int idx = blockIdx.x * 256 + threadIdx.x;   // over H*E = 131072
    int e = idx & (E_ - 1), h = idx >> 10;
    o[(size_t)h * E_ + e] = f2bf(W[(size_t)e * H_ + h]);
}

// ---------------- fused QKV projection: (M,E) @ (E,H)x3 -> bf16 -------------
__global__ __launch_bounds__(256) void proj_kernel(const float* __restrict__ x,
                                                   const unsigned short* __restrict__ WT,
                                                   unsigned short* __restrict__ QKV) {
    __shared__ unsigned short As[64][40];   // pad 32->40: 2-way bank conflicts only
    int tid = threadIdx.x;
    int wid = tid >> 6;
    int lane = tid & 63;
    int lrow = lane & 15;
    int lk = (lane >> 4) << 3;
    int row0 = blockIdx.x * 64;

    f32x4 acc[3][8];
#pragma unroll
    for (int w = 0; w < 3; ++w)
#pragma unroll
        for (int nf = 0; nf < 8; ++nf)
            acc[w][nf] = (f32x4){0.f, 0.f, 0.f, 0.f};

    int sr = tid >> 2;          // staging row 0..63
    int sc = (tid & 3) << 3;    // staging col 0,8,16,24

    for (int k0 = 0; k0 < E_; k0 += 32) {
        const float* src = x + (size_t)(row0 + sr) * E_ + k0 + sc;
        float4 f0 = *(const float4*)src;
        float4 f1 = *(const float4*)(src + 4);
        __syncthreads();   // WAR: previous iteration's reads done
        unsigned short tmp[8] = {f2bf(f0.x), f2bf(f0.y), f2bf(f0.z), f2bf(f0.w),
                                 f2bf(f1.x), f2bf(f1.y), f2bf(f1.z), f2bf(f1.w)};
        *(bf16x8*)&As[sr][sc] = *(const bf16x8*)tmp;
        __syncthreads();

        bf16x8 a = *(const bf16x8*)&As[wid * 16 + lrow][lk];
#pragma unroll
        for (int w = 0; w < 3; ++w) {
            const unsigned short* wt = WT + (size_t)w * H_ * E_;
#pragma unroll
            for (int nf = 0; nf < 8; ++nf) {
                bf16x8 b = *(const bf16x8*)&wt[(size_t)(nf * 16 + lrow) * E_ + k0 + lk];
                acc[w][nf] = __builtin_amdgcn_mfma_f32_16x16x32_bf16(a, b, acc[w][nf], 0, 0, 0);
            }
        }
    }
    // D layout: col = lane&15, row = (lane>>4)*4 + reg   [verified mapping]
    int drow0 = row0 + wid * 16 + ((lane >> 4) << 2);
#pragma unroll
    for (int w = 0; w < 3; ++w) {
        unsigned short* outp = QKV + (size_t)w * M_ * H_;
#pragma unroll
        for (int nf = 0; nf < 8; ++nf) {
            int col = nf * 16 + lrow;
#pragma unroll
            for (int r = 0; r < 4; ++r)
                outp[(size_t)(drow0 + r) * H_ + col] = f2bf(acc[w][nf][r]);
        }
    }
}

// ---------------- flash attention, causal, 64-row Q tile --------------------
__global__ __launch_bounds__(256) void attn_kernel(const unsigned short* __restrict__ QKV,
                                                   float* __restrict__ out) {
    __shared__ unsigned short Ks[64][136];   // K tile row-major, pad -> 2-way
    __shared__ unsigned short Vt[128][72];   // V tile transposed (H x keys), pad
    __shared__ unsigned short Ps[4][16][72]; // per-wave P tile (16 q x 64 keys)

    const unsigned short* Q = QKV;
    const unsigned short* K = QKV + (size_t)M_ * H_;
    const unsigned short* V = QKV + (size_t)2 * M_ * H_;

    int tid = threadIdx.x;
    int wid = tid >> 6;
    int lane = tid & 63;
    int lrow = lane & 15;
    int lk = (lane >> 4) << 3;
    int b = blockIdx.y;
    int q0 = blockIdx.x * 64;
    size_t rbase = (size_t)b * C_ + q0;

    // Q fragments (A operand): A[m=lane&15][k=(lane>>4)*8+j]
    bf16x8 qf[4];
#pragma unroll
    for (int kf = 0; kf < 4; ++kf)
        qf[kf] = *(const bf16x8*)&Q[(rbase + wid * 16 + lrow) * H_ + kf * 32 + lk];

    f32x4 o[8];
#pragma unroll
    for (int nf = 0; nf < 8; ++nf) o[nf] = (f32x4){0.f, 0.f, 0.f, 0.f};
    float m[4] = {-INFINITY, -INFINITY, -INFINITY, -INFINITY};
    float l[4] = {0.f, 0.f, 0.f, 0.f};
    const float scale = 0.03125f;   // 1/sqrt(E)=1/32

    int sr = tid >> 2;
    int sc0 = (tid & 3) << 5;

    int ntiles = blockIdx.x + 1;    // causal: kv tiles up to & incl. diagonal
    for (int t = 0; t < ntiles; ++t) {
        int kv0 = t * 64;
        size_t kbase = (size_t)b * C_ + kv0;
        __syncthreads();
        // stage K row-major + V transposed
#pragma unroll
        for (int i = 0; i < 4; ++i) {
            int c = sc0 + i * 8;
            *(bf16x8*)&Ks[sr][c] = *(const bf16x8*)&K[(kbase + sr) * H_ + c];
            bf16x8 vv = *(const bf16x8*)&V[(kbase + sr) * H_ + c];
#pragma unroll
            for (int j = 0; j < 8; ++j)
                Vt[c + j][sr] = ((unsigned short*)&vv)[j];
        }
        __syncthreads();

        // S = Q K^T  (4 n-frags of 16 keys)
        f32x4 s[4];
#pragma unroll
        for (int nf = 0; nf < 4; ++nf) {
            s[nf] = (f32x4){0.f, 0.f, 0.f, 0.f};
#pragma unroll
            for (int kf = 0; kf < 4; ++kf) {
                bf16x8 kb = *(const bf16x8*)&Ks[nf * 16 + lrow][kf * 32 + lk];
                s[nf] = __builtin_amdgcn_mfma_f32_16x16x32_bf16(qf[kf], kb, s[nf], 0, 0, 0);
            }
        }
        // scale + causal mask + tile rowmax
        int qrow = q0 + wid * 16 + ((lane >> 4) << 2);
        float mt[4] = {-INFINITY, -INFINITY, -INFINITY, -INFINITY};
#pragma unroll
        for (int nf = 0; nf < 4; ++nf) {
            int key = kv0 + nf * 16 + lrow;
#pragma unroll
            for (int r = 0; r < 4; ++r) {
                float sv = s[nf][r] * scale;
                sv = (key <= qrow + r) ? sv : -INFINITY;
                s[nf][r] = sv;
                mt[r] = fmaxf(mt[r], sv);
            }
        }
#pragma unroll
        for (int r = 0; r < 4; ++r)
#pragma unroll
            for (int off = 1; off < 16; off <<= 1)
                mt[r] = fmaxf(mt[r], __shfl_xor(mt[r], off));

        float corr[4];
#pragma unroll
        for (int r = 0; r < 4; ++r) {
            float mn = fmaxf(m[r], mt[r]);
            corr[r] = __expf(m[r] - mn);   // exp(-inf - finite)=0 on first tile
            m[r] = mn;
        }
        float ps[4] = {0.f, 0.f, 0.f, 0.f};
#pragma unroll
        for (int nf = 0; nf < 4; ++nf) {
#pragma unroll
            for (int r = 0; r < 4; ++r) {
                float p = __expf(s[nf][r] - m[r]);   // masked -> exp(-inf)=0
                ps[r] += p;
                Ps[wid][((lane >> 4) << 2) + r][nf * 16 + lrow] = f2bf(p);
            }
        }
#pragma unroll
        for (int r = 0; r < 4; ++r) {
#pragma unroll
            for (int off = 1; off < 16; off <<= 1)
                ps[r] += __shfl_xor(ps[r], off);
            l[r] = l[r] * corr[r] + ps[r];
        }
#pragma unroll
        for (int nf = 0; nf < 8; ++nf)
#pragma unroll
            for (int r = 0; r < 4; ++r)
                o[nf][r] *= corr[r];

        // PV: O += P @ V   (P via per-wave LDS D->A relayout; wave-synchronous)
        bf16x8 pa[2];
#pragma unroll
        for (int kf2 = 0; kf2 < 2; ++kf2)
            pa[kf2] = *(const bf16x8*)&Ps[wid][lrow][kf2 * 32 + lk];
#pragma unroll
        for (int nf = 0; nf < 8; ++nf) {
#pragma unroll
            for (int kf2 = 0; kf2 < 2; ++kf2) {
                bf16x8 vb = *(const bf16x8*)&Vt[nf * 16 + lrow][kf2 * 32 + lk];
                o[nf] = __builtin_amdgcn_mfma_f32_16x16x32_bf16(pa[kf2], vb, o[nf], 0, 0, 0);
            }
        }
    }

    int drow = q0 + wid * 16 + ((lane >> 4) << 2);
#pragma unroll
    for (int nf = 0; nf < 8; ++nf) {
        int col = nf * 16 + lrow;
#pragma unroll
        for (int r = 0; r < 4; ++r)
            out[((size_t)b * C_ + drow + r) * H_ + col] = o[nf][r] / l[r];
    }
}

extern "C" void kernel_launch(void* const* d_in, const int* in_sizes, int n_in,
                              void* d_out, int out_size, void* d_ws, size_t ws_size,
                              hipStream_t stream) {
    const float* x  = (const float*)d_in[0];
    const float* Wq = (const float*)d_in[1];
    const float* Wk = (const float*)d_in[2];
    const float* Wv = (const float*)d_in[3];
    float* out = (float*)d_out;

    unsigned short* WT  = (unsigned short*)d_ws;               // 3 * H*E bf16 = 768 KB
    unsigned short* QKV = WT + (size_t)3 * H_ * E_;            // 3 * M*H bf16 = 12 MB

    wt_kernel<<<dim3(H_ * E_ / 256, 3), 256, 0, stream>>>(Wq, Wk, Wv, WT);
    proj_kernel<<<dim3(M_ / 64), 256, 0, stream>>>(x, WT, QKV);
    attn_kernel<<<dim3(C_ / 64, B_), 256, 0, stream>>>(QKV, out);
}

// Round 2
// 148.115 us; speedup vs baseline: 2.0472x; 2.0472x over previous
//
#include <hip/hip_runtime.h>
#include <hip/hip_bf16.h>
#include <stdint.h>

#define B_ 8
#define C_ 2048
#define E_ 1024
#define H_ 128
#define M_ (B_*C_)   // 16384 rows total

typedef __attribute__((ext_vector_type(8))) short bf16x8;
typedef __attribute__((ext_vector_type(4))) float f32x4;

__device__ __forceinline__ unsigned short f2bf(float f) {
    union { float f; unsigned int u; } v; v.f = f;
    unsigned int u = v.u;
    u += 0x7fff + ((u >> 16) & 1);   // RNE
    return (unsigned short)(u >> 16);
}

#define GLOAD_LDS16(g, l) \
    __builtin_amdgcn_global_load_lds((const __attribute__((address_space(1))) void*)(g), \
                                     (__attribute__((address_space(3))) void*)(l), 16, 0, 0)

// ---------------- W transpose+convert: (E,H) f32 -> (H,E) bf16, x3 ----------
__global__ __launch_bounds__(256) void wt_kernel(const float* __restrict__ Wq,
                                                 const float* __restrict__ Wk,
                                                 const float* __restrict__ Wv,
                                                 unsigned short* __restrict__ WT) {
    int z = blockIdx.y;
    const float* W = (z == 0) ? Wq : (z == 1) ? Wk : Wv;
    unsigned short* o = WT + (size_t)z * H_ * E_;
    int idx = blockIdx.x * 256 + threadIdx.x;   // over H*E = 131072
    int e = idx & (E_ - 1), h = idx >> 10;
    o[(size_t)h * E_ + e] = f2bf(W[(size_t)e * H_ + h]);
}

// ---------------- QKV projection: 64x128 tile, BK=64, swizzled LDS ----------
// blockIdx.y = which matrix (0=Q,1=K,2=V). V is written TRANSPOSED [b][h][c].
__global__ __launch_bounds__(256) void proj_kernel(const float* __restrict__ x,
                                                   const unsigned short* __restrict__ WT,
                                                   unsigned short* __restrict__ QKV) {
    __shared__ __align__(16) unsigned short As[64][64];    // 8 KB, XOR-swizzled granules
    __shared__ __align__(16) unsigned short Bs[128][64];   // 16 KB, XOR-swizzled granules

    const int tid = threadIdx.x;
    const int wid = tid >> 6, lane = tid & 63;
    const int lrow = lane & 15, lq = lane >> 4;
    const int wr = wid >> 1, wc = wid & 1;     // wave tile: rows wr*32, cols wc*64
    const int row0 = blockIdx.x * 64;
    const int w = blockIdx.y;
    const unsigned short* wt = WT + (size_t)w * H_ * E_;

    const int arow = tid >> 2;          // A staging: row 0..63
    const int ag0 = (tid & 3) * 2;      // 2 granules (16B) per thread

    f32x4 acc[2][4];
#pragma unroll
    for (int mi = 0; mi < 2; ++mi)
#pragma unroll
        for (int ni = 0; ni < 4; ++ni) acc[mi][ni] = (f32x4){0.f, 0.f, 0.f, 0.f};

    for (int k0 = 0; k0 < E_; k0 += 64) {
        // A: global fp32 -> regs (issued before barrier to hide latency)
        const float* xs = x + (size_t)(row0 + arow) * E_ + k0 + ag0 * 8;
        float4 a0 = *(const float4*)xs;
        float4 a1 = *(const float4*)(xs + 4);
        float4 a2 = *(const float4*)(xs + 8);
        float4 a3 = *(const float4*)(xs + 12);
        __syncthreads();   // WAR: previous iteration's LDS reads done
        {
            unsigned short t0[8] = {f2bf(a0.x), f2bf(a0.y), f2bf(a0.z), f2bf(a0.w),
                                    f2bf(a1.x), f2bf(a1.y), f2bf(a1.z), f2bf(a1.w)};
            unsigned short t1[8] = {f2bf(a2.x), f2bf(a2.y), f2bf(a2.z), f2bf(a2.w),
                                    f2bf(a3.x), f2bf(a3.y), f2bf(a3.z), f2bf(a3.w)};
            *(bf16x8*)&As[arow][(ag0 ^ (arow & 7)) * 8]     = *(const bf16x8*)t0;
            *(bf16x8*)&As[arow][((ag0 + 1) ^ (arow & 7)) * 8] = *(const bf16x8*)t1;
        }
        // B: global_load_lds, linear LDS dest + pre-swizzled global source
#pragma unroll
        for (int i = 0; i < 4; ++i) {
            int brow = i * 32 + (tid >> 3);
            int bg = (tid & 7) ^ (brow & 7);
            const unsigned short* src = wt + (size_t)brow * E_ + k0 + bg * 8;
            char* dst = (char*)Bs + i * 4096 + tid * 16;
            GLOAD_LDS16(src, dst);
        }
        __syncthreads();   // drains vmcnt(0): B staged, A written
#pragma unroll
        for (int ks = 0; ks < 2; ++ks) {
            const int g = ks * 4 + lq;
            bf16x8 af[2], bfr[4];
#pragma unroll
            for (int mi = 0; mi < 2; ++mi) {
                int ra = wr * 32 + mi * 16 + lrow;
                af[mi] = *(const bf16x8*)&As[ra][(g ^ (ra & 7)) * 8];
            }
#pragma unroll
            for (int ni = 0; ni < 4; ++ni) {
                int rb = wc * 64 + ni * 16 + lrow;
                bfr[ni] = *(const bf16x8*)&Bs[rb][(g ^ (rb & 7)) * 8];
            }
#pragma unroll
            for (int mi = 0; mi < 2; ++mi)
#pragma unroll
                for (int ni = 0; ni < 4; ++ni)
                    acc[mi][ni] = __builtin_amdgcn_mfma_f32_16x16x32_bf16(af[mi], bfr[ni], acc[mi][ni], 0, 0, 0);
        }
    }

    // D layout: col = lane&15, row = lq*4 + reg
    if (w < 2) {
        const float qs = (w == 0) ? 0.03125f : 1.0f;   // fold 1/sqrt(E) into Q (exact pow2)
        unsigned short* outp = QKV + (size_t)w * M_ * H_;
#pragma unroll
        for (int mi = 0; mi < 2; ++mi) {
            int r0 = row0 + wr * 32 + mi * 16 + lq * 4;
#pragma unroll
            for (int ni = 0; ni < 4; ++ni) {
                int col = wc * 64 + ni * 16 + lrow;
#pragma unroll
                for (int r = 0; r < 4; ++r)
                    outp[(size_t)(r0 + r) * H_ + col] = f2bf(acc[mi][ni][r] * qs);
            }
        }
    } else {
        // V transposed: VT[(b*H + h)*C + c], 4 consecutive c per lane -> 8B store
        unsigned short* vt = QKV + (size_t)2 * M_ * H_;
        int b = row0 / C_;
        int cbase = row0 % C_;
#pragma unroll
        for (int mi = 0; mi < 2; ++mi) {
            int c0 = cbase + wr * 32 + mi * 16 + lq * 4;
#pragma unroll
            for (int ni = 0; ni < 4; ++ni) {
                int h = wc * 64 + ni * 16 + lrow;
                __align__(8) unsigned short p[4] = {f2bf(acc[mi][ni][0]), f2bf(acc[mi][ni][1]),
                                                    f2bf(acc[mi][ni][2]), f2bf(acc[mi][ni][3])};
                *(uint2*)&vt[((size_t)b * H_ + h) * C_ + c0] = *(const uint2*)p;
            }
        }
    }
}

// ---------------- flash attention, causal, staging-free, barrier-free -------
// grid (B, C/64): blockIdx.x = batch (XCD affinity: id%8 = b), blockIdx.y = qtile
__global__ __launch_bounds__(256) void attn_kernel(const unsigned short* __restrict__ QKV,
                                                   float* __restrict__ out) {
    __shared__ __align__(16) unsigned short Ps[4][16][72];  // per-wave P relayout

    const unsigned short* Q  = QKV;
    const unsigned short* K  = QKV + (size_t)M_ * H_;
    const unsigned short* VT = QKV + (size_t)2 * M_ * H_;

    const int tid = threadIdx.x, wid = tid >> 6, lane = tid & 63;
    const int lrow = lane & 15, lq = lane >> 4, lk = lq * 8;
    const int b = blockIdx.x;
    const int j = blockIdx.y;
    const int q0w = j * 64 + wid * 16;
    const unsigned short* Kb  = K  + (size_t)b * C_ * H_;
    const unsigned short* VTb = VT + (size_t)b * H_ * C_;
    const int qrow0 = q0w + lq * 4;

    bf16x8 qf[4];
#pragma unroll
    for (int kf = 0; kf < 4; ++kf)
        qf[kf] = *(const bf16x8*)&Q[((size_t)b * C_ + q0w + lrow) * H_ + kf * 32 + lk];

    f32x4 o[8];
#pragma unroll
    for (int nf = 0; nf < 8; ++nf) o[nf] = (f32x4){0.f, 0.f, 0.f, 0.f};
    float m[4] = {-INFINITY, -INFINITY, -INFINITY, -INFINITY};
    float l[4] = {0.f, 0.f, 0.f, 0.f};

    for (int t = 0; t <= j; ++t) {
        const int kv0 = t * 64;
        // S = Q K^T  (Q pre-scaled by 1/32 in proj)
        f32x4 s[4];
#pragma unroll
        for (int nf = 0; nf < 4; ++nf) {
            s[nf] = (f32x4){0.f, 0.f, 0.f, 0.f};
#pragma unroll
            for (int kf = 0; kf < 4; ++kf) {
                bf16x8 kb = *(const bf16x8*)&Kb[(size_t)(kv0 + nf * 16 + lrow) * H_ + kf * 32 + lk];
                s[nf] = __builtin_amdgcn_mfma_f32_16x16x32_bf16(qf[kf], kb, s[nf], 0, 0, 0);
            }
        }
        // prefetch V fragments (latency hides under softmax)
        bf16x8 vb[8][2];
#pragma unroll
        for (int nf = 0; nf < 8; ++nf)
#pragma unroll
            for (int kf2 = 0; kf2 < 2; ++kf2)
                vb[nf][kf2] = *(const bf16x8*)&VTb[(size_t)(nf * 16 + lrow) * C_ + kv0 + kf2 * 32 + lk];

        if (t == j) {   // only the diagonal tile needs masking
#pragma unroll
            for (int nf = 0; nf < 4; ++nf) {
                int key = kv0 + nf * 16 + lrow;
#pragma unroll
                for (int r = 0; r < 4; ++r)
                    if (key > qrow0 + r) s[nf][r] = -INFINITY;
            }
        }
        // online softmax (16-lane group reduce)
        float mt[4] = {-INFINITY, -INFINITY, -INFINITY, -INFINITY};
#pragma unroll
        for (int nf = 0; nf < 4; ++nf)
#pragma unroll
            for (int r = 0; r < 4; ++r) mt[r] = fmaxf(mt[r], s[nf][r]);
#pragma unroll
        for (int r = 0; r < 4; ++r)
#pragma unroll
            for (int off = 1; off < 16; off <<= 1)
                mt[r] = fmaxf(mt[r], __shfl_xor(mt[r], off));

        float corr[4];
#pragma unroll
        for (int r = 0; r < 4; ++r) {
            float mn = fmaxf(m[r], mt[r]);
            corr[r] = __expf(m[r] - mn);   // first tile: exp(-inf)=0
            m[r] = mn;
        }
        float ps[4] = {0.f, 0.f, 0.f, 0.f};
#pragma unroll
        for (int nf = 0; nf < 4; ++nf)
#pragma unroll
            for (int r = 0; r < 4; ++r) {
                float p = __expf(s[nf][r] - m[r]);   // masked -> 0
                ps[r] += p;
                Ps[wid][lq * 4 + r][nf * 16 + lrow] = f2bf(p);
            }
#pragma unroll
        for (int r = 0; r < 4; ++r) {
#pragma unroll
            for (int off = 1; off < 16; off <<= 1) ps[r] += __shfl_xor(ps[r], off);
            l[r] = l[r] * corr[r] + ps[r];
        }
#pragma unroll
        for (int nf = 0; nf < 8; ++nf)
#pragma unroll
            for (int r = 0; r < 4; ++r) o[nf][r] *= corr[r];

        // PV: O += P @ V  (wave-synchronous D->A relayout via Ps)
        bf16x8 pa[2];
#pragma unroll
        for (int kf2 = 0; kf2 < 2; ++kf2)
            pa[kf2] = *(const bf16x8*)&Ps[wid][lrow][kf2 * 32 + lk];
#pragma unroll
        for (int nf = 0; nf < 8; ++nf)
#pragma unroll
            for (int kf2 = 0; kf2 < 2; ++kf2)
                o[nf] = __builtin_amdgcn_mfma_f32_16x16x32_bf16(pa[kf2], vb[nf][kf2], o[nf], 0, 0, 0);
    }

#pragma unroll
    for (int nf = 0; nf < 8; ++nf) {
        int col = nf * 16 + lrow;
#pragma unroll
        for (int r = 0; r < 4; ++r)
            out[((size_t)b * C_ + qrow0 + r) * H_ + col] = o[nf][r] / l[r];
    }
}

extern "C" void kernel_launch(void* const* d_in, const int* in_sizes, int n_in,
                              void* d_out, int out_size, void* d_ws, size_t ws_size,
                              hipStream_t stream) {
    const float* x  = (const float*)d_in[0];
    const float* Wq = (const float*)d_in[1];
    const float* Wk = (const float*)d_in[2];
    const float* Wv = (const float*)d_in[3];
    float* out = (float*)d_out;

    unsigned short* WT  = (unsigned short*)d_ws;        // 3 * H*E bf16 = 768 KB
    unsigned short* QKV = WT + (size_t)3 * H_ * E_;     // Q, K, V^T bf16 = 12 MB

    wt_kernel<<<dim3(H_ * E_ / 256, 3), 256, 0, stream>>>(Wq, Wk, Wv, WT);
    proj_kernel<<<dim3(M_ / 64, 3), 256, 0, stream>>>(x, WT, QKV);
    attn_kernel<<<dim3(B_, C_ / 64), 256, 0, stream>>>(QKV, out);
}

// Round 3
// 98.380 us; speedup vs baseline: 3.0822x; 1.5055x over previous
//
#include <hip/hip_runtime.h>
#include <hip/hip_bf16.h>
#include <stdint.h>

#define B_ 8
#define C_ 2048
#define E_ 1024
#define H_ 128
#define M_ (B_*C_)   // 16384 rows total

typedef __attribute__((ext_vector_type(8))) short bf16x8;
typedef __attribute__((ext_vector_type(4))) float f32x4;

__device__ __forceinline__ unsigned short f2bf(float f) {
    union { float f; unsigned int u; } v; v.f = f;
    unsigned int u = v.u;
    u += 0x7fff + ((u >> 16) & 1);   // RNE
    return (unsigned short)(u >> 16);
}

#define GLOAD_LDS16(g, l) \
    __builtin_amdgcn_global_load_lds((const __attribute__((address_space(1))) void*)(g), \
                                     (__attribute__((address_space(3))) void*)(l), 16, 0, 0)

// ---------------- W transpose+convert: (E,H) f32 -> (H,E) bf16, x3 ----------
__global__ __launch_bounds__(256) void wt_kernel(const float* __restrict__ Wq,
                                                 const float* __restrict__ Wk,
                                                 const float* __restrict__ Wv,
                                                 unsigned short* __restrict__ WT) {
    int z = blockIdx.y;
    const float* W = (z == 0) ? Wq : (z == 1) ? Wk : Wv;
    unsigned short* o = WT + (size_t)z * H_ * E_;
    int idx = blockIdx.x * 256 + threadIdx.x;   // over H*E = 131072
    int e = idx & (E_ - 1), h = idx >> 10;
    o[(size_t)h * E_ + e] = f2bf(W[(size_t)e * H_ + h]);
}

// ---------------- QKV projection: 64x128 tile, BK=64, swizzled LDS ----------
// blockIdx.y = which matrix (0=Q,1=K,2=V). V is written TRANSPOSED [b][h][c].
__global__ __launch_bounds__(256) void proj_kernel(const float* __restrict__ x,
                                                   const unsigned short* __restrict__ WT,
                                                   unsigned short* __restrict__ QKV) {
    __shared__ __align__(16) unsigned short As[64][64];    // 8 KB, XOR-swizzled granules
    __shared__ __align__(16) unsigned short Bs[128][64];   // 16 KB, XOR-swizzled granules

    const int tid = threadIdx.x;
    const int wid = tid >> 6, lane = tid & 63;
    const int lrow = lane & 15, lq = lane >> 4;
    const int wr = wid >> 1, wc = wid & 1;     // wave tile: rows wr*32, cols wc*64
    const int row0 = blockIdx.x * 64;
    const int w = blockIdx.y;
    const unsigned short* wt = WT + (size_t)w * H_ * E_;

    const int arow = tid >> 2;          // A staging: row 0..63
    const int ag0 = (tid & 3) * 2;      // 2 granules (16B) per thread

    f32x4 acc[2][4];
#pragma unroll
    for (int mi = 0; mi < 2; ++mi)
#pragma unroll
        for (int ni = 0; ni < 4; ++ni) acc[mi][ni] = (f32x4){0.f, 0.f, 0.f, 0.f};

    for (int k0 = 0; k0 < E_; k0 += 64) {
        // A: global fp32 -> regs (issued before barrier to hide latency)
        const float* xs = x + (size_t)(row0 + arow) * E_ + k0 + ag0 * 8;
        float4 a0 = *(const float4*)xs;
        float4 a1 = *(const float4*)(xs + 4);
        float4 a2 = *(const float4*)(xs + 8);
        float4 a3 = *(const float4*)(xs + 12);
        __syncthreads();   // WAR: previous iteration's LDS reads done
        {
            unsigned short t0[8] = {f2bf(a0.x), f2bf(a0.y), f2bf(a0.z), f2bf(a0.w),
                                    f2bf(a1.x), f2bf(a1.y), f2bf(a1.z), f2bf(a1.w)};
            unsigned short t1[8] = {f2bf(a2.x), f2bf(a2.y), f2bf(a2.z), f2bf(a2.w),
                                    f2bf(a3.x), f2bf(a3.y), f2bf(a3.z), f2bf(a3.w)};
            *(bf16x8*)&As[arow][(ag0 ^ (arow & 7)) * 8]     = *(const bf16x8*)t0;
            *(bf16x8*)&As[arow][((ag0 + 1) ^ (arow & 7)) * 8] = *(const bf16x8*)t1;
        }
        // B: global_load_lds, linear LDS dest + pre-swizzled global source
#pragma unroll
        for (int i = 0; i < 4; ++i) {
            int brow = i * 32 + (tid >> 3);
            int bg = (tid & 7) ^ (brow & 7);
            const unsigned short* src = wt + (size_t)brow * E_ + k0 + bg * 8;
            char* dst = (char*)Bs + i * 4096 + tid * 16;
            GLOAD_LDS16(src, dst);
        }
        __syncthreads();   // drains vmcnt(0): B staged, A written
#pragma unroll
        for (int ks = 0; ks < 2; ++ks) {
            const int g = ks * 4 + lq;
            bf16x8 af[2], bfr[4];
#pragma unroll
            for (int mi = 0; mi < 2; ++mi) {
                int ra = wr * 32 + mi * 16 + lrow;
                af[mi] = *(const bf16x8*)&As[ra][(g ^ (ra & 7)) * 8];
            }
#pragma unroll
            for (int ni = 0; ni < 4; ++ni) {
                int rb = wc * 64 + ni * 16 + lrow;
                bfr[ni] = *(const bf16x8*)&Bs[rb][(g ^ (rb & 7)) * 8];
            }
#pragma unroll
            for (int mi = 0; mi < 2; ++mi)
#pragma unroll
                for (int ni = 0; ni < 4; ++ni)
                    acc[mi][ni] = __builtin_amdgcn_mfma_f32_16x16x32_bf16(af[mi], bfr[ni], acc[mi][ni], 0, 0, 0);
        }
    }

    // D layout: col = lane&15, row = lq*4 + reg
    if (w < 2) {
        const float qs = (w == 0) ? 0.03125f : 1.0f;   // fold 1/sqrt(E) into Q (exact pow2)
        unsigned short* outp = QKV + (size_t)w * M_ * H_;
#pragma unroll
        for (int mi = 0; mi < 2; ++mi) {
            int r0 = row0 + wr * 32 + mi * 16 + lq * 4;
#pragma unroll
            for (int ni = 0; ni < 4; ++ni) {
                int col = wc * 64 + ni * 16 + lrow;
#pragma unroll
                for (int r = 0; r < 4; ++r)
                    outp[(size_t)(r0 + r) * H_ + col] = f2bf(acc[mi][ni][r] * qs);
            }
        }
    } else {
        // V transposed: VT[(b*H + h)*C + c], 4 consecutive c per lane -> 8B store
        unsigned short* vt = QKV + (size_t)2 * M_ * H_;
        int b = row0 / C_;
        int cbase = row0 % C_;
#pragma unroll
        for (int mi = 0; mi < 2; ++mi) {
            int c0 = cbase + wr * 32 + mi * 16 + lq * 4;
#pragma unroll
            for (int ni = 0; ni < 4; ++ni) {
                int h = wc * 64 + ni * 16 + lrow;
                __align__(8) unsigned short p[4] = {f2bf(acc[mi][ni][0]), f2bf(acc[mi][ni][1]),
                                                    f2bf(acc[mi][ni][2]), f2bf(acc[mi][ni][3])};
                *(uint2*)&vt[((size_t)b * H_ + h) * C_ + c0] = *(const uint2*)p;
            }
        }
    }
}

// ---------------- flash attention: dbuf LDS staging, swizzled, pipelined ----
// grid (B, C/64): blockIdx.x = batch (XCD affinity: linear id % 8 = b)
__global__ __launch_bounds__(256) void attn_kernel(const unsigned short* __restrict__ QKV,
                                                   float* __restrict__ out) {
    __shared__ __align__(16) unsigned short Ks[2][64][128];   // K tile, XOR-swz granules
    __shared__ __align__(16) unsigned short Vt[2][128][64];   // V^T tile, XOR-swz granules
    __shared__ __align__(16) unsigned short Ps[4][16][72];    // per-wave P relayout

    const unsigned short* Q  = QKV;
    const unsigned short* K  = QKV + (size_t)M_ * H_;
    const unsigned short* VT = QKV + (size_t)2 * M_ * H_;

    const int tid = threadIdx.x, wid = tid >> 6, lane = tid & 63;
    const int lrow = lane & 15, lq = lane >> 4, lk = lq * 8;
    const int b = blockIdx.x;
    const int j = blockIdx.y;
    const int q0w = j * 64 + wid * 16;
    const unsigned short* Kb  = K  + (size_t)b * C_ * H_;
    const unsigned short* VTb = VT + (size_t)b * H_ * C_;
    const int qrow0 = q0w + lq * 4;

    const int krow = tid >> 4, kg = tid & 15;   // K staging: 16 rows/shot, 16 granules/row
    const int vrow = tid >> 3, vg = tid & 7;    // V staging: 32 rows/shot, 8 granules/row

    bf16x8 qf[4];
#pragma unroll
    for (int kf = 0; kf < 4; ++kf)
        qf[kf] = *(const bf16x8*)&Q[((size_t)b * C_ + q0w + lrow) * H_ + kf * 32 + lk];

    f32x4 o[8];
#pragma unroll
    for (int nf = 0; nf < 8; ++nf) o[nf] = (f32x4){0.f, 0.f, 0.f, 0.f};
    float m[4] = {-INFINITY, -INFINITY, -INFINITY, -INFINITY};
    float l[4] = {0.f, 0.f, 0.f, 0.f};

    auto STAGE = [&](int buf, int t) {
        const int kv0 = t * 64;
#pragma unroll
        for (int s = 0; s < 4; ++s) {       // K tile: 64 rows x 256B
            int r = s * 16 + krow;
            GLOAD_LDS16(&Kb[(size_t)(kv0 + r) * H_ + ((kg ^ (r & 15)) * 8)],
                        (char*)&Ks[buf][0][0] + s * 4096 + tid * 16);
        }
#pragma unroll
        for (int s = 0; s < 4; ++s) {       // V^T tile: 128 rows x 128B
            int h = s * 32 + vrow;
            GLOAD_LDS16(&VTb[(size_t)h * C_ + kv0 + ((vg ^ (h & 7)) * 8)],
                        (char*)&Vt[buf][0][0] + s * 4096 + tid * 16);
        }
    };

    STAGE(0, 0);

    for (int t = 0; t <= j; ++t) {
        const int cur = t & 1;
        __syncthreads();                 // drains vmcnt: tile t staged; prev reads done
        if (t < j) STAGE(cur ^ 1, t + 1);   // overlap next-tile staging with compute

        const int kv0 = t * 64;
        // S = Q K^T  (Q pre-scaled by 1/32 in proj)
        f32x4 s[4];
#pragma unroll
        for (int nf = 0; nf < 4; ++nf) {
            s[nf] = (f32x4){0.f, 0.f, 0.f, 0.f};
            const int rk = nf * 16 + lrow;
#pragma unroll
            for (int kf = 0; kf < 4; ++kf) {
                bf16x8 kb = *(const bf16x8*)&Ks[cur][rk][((kf * 4 + lq) ^ (rk & 15)) * 8];
                s[nf] = __builtin_amdgcn_mfma_f32_16x16x32_bf16(qf[kf], kb, s[nf], 0, 0, 0);
            }
        }
        // V fragments from LDS (cheap; drain under softmax)
        bf16x8 vb[8][2];
#pragma unroll
        for (int nf = 0; nf < 8; ++nf) {
            const int h = nf * 16 + lrow;
#pragma unroll
            for (int kf2 = 0; kf2 < 2; ++kf2)
                vb[nf][kf2] = *(const bf16x8*)&Vt[cur][h][((kf2 * 4 + lq) ^ (h & 7)) * 8];
        }

        if (t == j) {   // only diagonal tile masks
#pragma unroll
            for (int nf = 0; nf < 4; ++nf) {
                int key = kv0 + nf * 16 + lrow;
#pragma unroll
                for (int r = 0; r < 4; ++r)
                    if (key > qrow0 + r) s[nf][r] = -INFINITY;
            }
        }
        // online softmax (16-lane group reduce)
        float mt[4] = {-INFINITY, -INFINITY, -INFINITY, -INFINITY};
#pragma unroll
        for (int nf = 0; nf < 4; ++nf)
#pragma unroll
            for (int r = 0; r < 4; ++r) mt[r] = fmaxf(mt[r], s[nf][r]);
#pragma unroll
        for (int r = 0; r < 4; ++r)
#pragma unroll
            for (int off = 1; off < 16; off <<= 1)
                mt[r] = fmaxf(mt[r], __shfl_xor(mt[r], off));

        float corr[4];
#pragma unroll
        for (int r = 0; r < 4; ++r) {
            float mn = fmaxf(m[r], mt[r]);
            corr[r] = __expf(m[r] - mn);   // first tile: exp(-inf)=0
            m[r] = mn;
        }
        float ps[4] = {0.f, 0.f, 0.f, 0.f};
#pragma unroll
        for (int nf = 0; nf < 4; ++nf)
#pragma unroll
            for (int r = 0; r < 4; ++r) {
                float p = __expf(s[nf][r] - m[r]);   // masked -> 0
                ps[r] += p;
                Ps[wid][lq * 4 + r][nf * 16 + lrow] = f2bf(p);
            }
#pragma unroll
        for (int r = 0; r < 4; ++r) {
#pragma unroll
            for (int off = 1; off < 16; off <<= 1) ps[r] += __shfl_xor(ps[r], off);
            l[r] = l[r] * corr[r] + ps[r];
        }
#pragma unroll
        for (int nf = 0; nf < 8; ++nf)
#pragma unroll
            for (int r = 0; r < 4; ++r) o[nf][r] *= corr[r];

        // PV: O += P @ V  (wave-synchronous D->A relayout via Ps)
        bf16x8 pa[2];
#pragma unroll
        for (int kf2 = 0; kf2 < 2; ++kf2)
            pa[kf2] = *(const bf16x8*)&Ps[wid][lrow][kf2 * 32 + lk];
#pragma unroll
        for (int nf = 0; nf < 8; ++nf)
#pragma unroll
            for (int kf2 = 0; kf2 < 2; ++kf2)
                o[nf] = __builtin_amdgcn_mfma_f32_16x16x32_bf16(pa[kf2], vb[nf][kf2], o[nf], 0, 0, 0);
    }

#pragma unroll
    for (int nf = 0; nf < 8; ++nf) {
        int col = nf * 16 + lrow;
#pragma unroll
        for (int r = 0; r < 4; ++r)
            out[((size_t)b * C_ + qrow0 + r) * H_ + col] = o[nf][r] / l[r];
    }
}

extern "C" void kernel_launch(void* const* d_in, const int* in_sizes, int n_in,
                              void* d_out, int out_size, void* d_ws, size_t ws_size,
                              hipStream_t stream) {
    const float* x  = (const float*)d_in[0];
    const float* Wq = (const float*)d_in[1];
    const float* Wk = (const float*)d_in[2];
    const float* Wv = (const float*)d_in[3];
    float* out = (float*)d_out;

    unsigned short* WT  = (unsigned short*)d_ws;        // 3 * H*E bf16 = 768 KB
    unsigned short* QKV = WT + (size_t)3 * H_ * E_;     // Q, K, V^T bf16 = 12 MB

    wt_kernel<<<dim3(H_ * E_ / 256, 3), 256, 0, stream>>>(Wq, Wk, Wv, WT);
    proj_kernel<<<dim3(M_ / 64, 3), 256, 0, stream>>>(x, WT, QKV);
    attn_kernel<<<dim3(B_, C_ / 64), 256, 0, stream>>>(QKV, out);
}

// Round 4
// 81.386 us; speedup vs baseline: 3.7257x; 1.2088x over previous
//
#include <hip/hip_runtime.h>
#include <hip/hip_bf16.h>
#include <stdint.h>

#define B_ 8
#define C_ 2048
#define E_ 1024
#define H_ 128
#define M_ (B_*C_)      // 16384 rows total
#define SLOTS_B 144     // chunks per batch: sum_j ceil((j+1)/4), j<32

typedef __attribute__((ext_vector_type(8))) short bf16x8;
typedef __attribute__((ext_vector_type(4))) float f32x4;

__device__ __forceinline__ unsigned short f2bf(float f) {
    union { float f; unsigned int u; } v; v.f = f;
    unsigned int u = v.u;
    u += 0x7fff + ((u >> 16) & 1);   // RNE
    return (unsigned short)(u >> 16);
}
__device__ __forceinline__ float bf2f(unsigned short u) {
    union { unsigned int i; float f; } v; v.i = ((unsigned int)u) << 16; return v.f;
}

#define GLOAD_LDS16(g, l) \
    __builtin_amdgcn_global_load_lds((const __attribute__((address_space(1))) void*)(g), \
                                     (__attribute__((address_space(3))) void*)(l), 16, 0, 0)

// ---------------- W transpose+convert: (E,H) f32 -> (H,E) bf16, x3 ----------
__global__ __launch_bounds__(256) void wt_kernel(const float* __restrict__ Wq,
                                                 const float* __restrict__ Wk,
                                                 const float* __restrict__ Wv,
                                                 unsigned short* __restrict__ WT) {
    int z = blockIdx.y;
    const float* W = (z == 0) ? Wq : (z == 1) ? Wk : Wv;
    unsigned short* o = WT + (size_t)z * H_ * E_;
    int idx = blockIdx.x * 256 + threadIdx.x;
    int e = idx & (E_ - 1), h = idx >> 10;
    o[(size_t)h * E_ + e] = f2bf(W[(size_t)e * H_ + h]);
}

// ---------------- fused QKV projection: reads x ONCE, BM=32 ------------------
__global__ __launch_bounds__(256) void proj_kernel(const float* __restrict__ x,
                                                   const unsigned short* __restrict__ WT,
                                                   unsigned short* __restrict__ QKV) {
    __shared__ __align__(16) unsigned short As[32][64];        // 4 KB
    __shared__ __align__(16) unsigned short Bs[3][128][64];    // 48 KB

    const int tid = threadIdx.x;
    const int wid = tid >> 6, lane = tid & 63;
    const int lrow = lane & 15, lq = lane >> 4;
    const int wc = wid;                 // wave cols: wc*32 within each W
    const int row0 = blockIdx.x * 32;

    const int arow = tid >> 3;          // A staging row 0..31
    const int ag = tid & 7;             // granule 0..7

    f32x4 acc[3][2][2];
#pragma unroll
    for (int w = 0; w < 3; ++w)
#pragma unroll
        for (int mi = 0; mi < 2; ++mi)
#pragma unroll
            for (int ni = 0; ni < 2; ++ni) acc[w][mi][ni] = (f32x4){0.f, 0.f, 0.f, 0.f};

    for (int k0 = 0; k0 < E_; k0 += 64) {
        const float* xs = x + (size_t)(row0 + arow) * E_ + k0 + ag * 8;
        float4 a0 = *(const float4*)xs;
        float4 a1 = *(const float4*)(xs + 4);
        __syncthreads();   // WAR: previous iteration's LDS reads done
        {
            unsigned short t0[8] = {f2bf(a0.x), f2bf(a0.y), f2bf(a0.z), f2bf(a0.w),
                                    f2bf(a1.x), f2bf(a1.y), f2bf(a1.z), f2bf(a1.w)};
            *(bf16x8*)&As[arow][(ag ^ (arow & 7)) * 8] = *(const bf16x8*)t0;
        }
        // stage all 3 W tiles: 12 gload_lds per thread, pre-swizzled source
#pragma unroll
        for (int w = 0; w < 3; ++w)
#pragma unroll
            for (int s = 0; s < 4; ++s) {
                int brow = s * 32 + (tid >> 3);
                int bg = (tid & 7) ^ (brow & 7);
                const unsigned short* src = WT + (size_t)w * H_ * E_ + (size_t)brow * E_ + k0 + bg * 8;
                char* dst = (char*)&Bs[w][0][0] + s * 4096 + tid * 16;
                GLOAD_LDS16(src, dst);
            }
        __syncthreads();   // drains vmcnt(0)
#pragma unroll
        for (int ks = 0; ks < 2; ++ks) {
            const int g = ks * 4 + lq;
            bf16x8 af[2];
#pragma unroll
            for (int mi = 0; mi < 2; ++mi) {
                int ra = mi * 16 + lrow;
                af[mi] = *(const bf16x8*)&As[ra][(g ^ (ra & 7)) * 8];
            }
#pragma unroll
            for (int w = 0; w < 3; ++w)
#pragma unroll
                for (int ni = 0; ni < 2; ++ni) {
                    int rb = wc * 32 + ni * 16 + lrow;
                    bf16x8 bb = *(const bf16x8*)&Bs[w][rb][(g ^ (rb & 7)) * 8];
#pragma unroll
                    for (int mi = 0; mi < 2; ++mi)
                        acc[w][mi][ni] = __builtin_amdgcn_mfma_f32_16x16x32_bf16(af[mi], bb, acc[w][mi][ni], 0, 0, 0);
                }
        }
    }

    // epilogue: Q (scaled 1/32), K row-major; V transposed [b][h][c]
#pragma unroll
    for (int w = 0; w < 2; ++w) {
        const float qs = (w == 0) ? 0.03125f : 1.0f;
        unsigned short* outp = QKV + (size_t)w * M_ * H_;
#pragma unroll
        for (int mi = 0; mi < 2; ++mi) {
            int r0 = row0 + mi * 16 + lq * 4;
#pragma unroll
            for (int ni = 0; ni < 2; ++ni) {
                int col = wc * 32 + ni * 16 + lrow;
#pragma unroll
                for (int r = 0; r < 4; ++r)
                    outp[(size_t)(r0 + r) * H_ + col] = f2bf(acc[w][mi][ni][r] * qs);
            }
        }
    }
    {
        unsigned short* vt = QKV + (size_t)2 * M_ * H_;
        int b = row0 / C_;
        int cbase = row0 % C_;
#pragma unroll
        for (int mi = 0; mi < 2; ++mi) {
            int c0 = cbase + mi * 16 + lq * 4;
#pragma unroll
            for (int ni = 0; ni < 2; ++ni) {
                int h = wc * 32 + ni * 16 + lrow;
                __align__(8) unsigned short p[4] = {f2bf(acc[2][mi][ni][0]), f2bf(acc[2][mi][ni][1]),
                                                    f2bf(acc[2][mi][ni][2]), f2bf(acc[2][mi][ni][3])};
                *(uint2*)&vt[((size_t)b * H_ + h) * C_ + c0] = *(const uint2*)p;
            }
        }
    }
}

// ---------------- split-KV flash attention chunks ---------------------------
// grid (144, B): blockIdx.x = chunk slot within batch, decoded to (j, c).
__global__ __launch_bounds__(256) void attn_kernel(const unsigned short* __restrict__ QKV,
                                                   unsigned short* __restrict__ PO,
                                                   float* __restrict__ ML,
                                                   float* __restrict__ out) {
    __shared__ __align__(16) unsigned short Ks[2][64][128];
    __shared__ __align__(16) unsigned short Vt[2][128][64];
    __shared__ __align__(16) unsigned short Ps[4][16][72];

    const unsigned short* Q  = QKV;
    const unsigned short* K  = QKV + (size_t)M_ * H_;
    const unsigned short* VT = QKV + (size_t)2 * M_ * H_;

    const int tid = threadIdx.x, wid = tid >> 6, lane = tid & 63;
    const int lrow = lane & 15, lq = lane >> 4, lk = lq * 8;
    const int rr = blockIdx.x;          // 0..143
    const int b = blockIdx.y;

    // decode rr -> (j, c): C(j) = j + 2q(q-1) + s*q, q=j>>2, s=j&3
    int j = 0;
#pragma unroll
    for (int jj = 1; jj < 32; ++jj) {
        int q = jj >> 2, s = jj & 3;
        if (jj + 2 * q * (q - 1) + s * q <= rr) j = jj;
    }
    const int qj = j >> 2, sj = j & 3;
    const int Cj = j + 2 * qj * (qj - 1) + sj * qj;
    const int c = rr - Cj;
    const int nch = qj + 1;
    const int t0 = c * 4;
    const int t1 = min(t0 + 4, j + 1);

    const int q0w = j * 64 + wid * 16;
    const unsigned short* Kb  = K  + (size_t)b * C_ * H_;
    const unsigned short* VTb = VT + (size_t)b * H_ * C_;
    const int qrow0 = q0w + lq * 4;

    const int krow = tid >> 4, kg = tid & 15;
    const int vrow = tid >> 3, vg = tid & 7;

    bf16x8 qf[4];
#pragma unroll
    for (int kf = 0; kf < 4; ++kf)
        qf[kf] = *(const bf16x8*)&Q[((size_t)b * C_ + q0w + lrow) * H_ + kf * 32 + lk];

    f32x4 o[8];
#pragma unroll
    for (int nf = 0; nf < 8; ++nf) o[nf] = (f32x4){0.f, 0.f, 0.f, 0.f};
    float m[4] = {-INFINITY, -INFINITY, -INFINITY, -INFINITY};
    float l[4] = {0.f, 0.f, 0.f, 0.f};

    auto STAGE = [&](int buf, int t) {
        const int kv0 = t * 64;
#pragma unroll
        for (int s = 0; s < 4; ++s) {
            int r = s * 16 + krow;
            GLOAD_LDS16(&Kb[(size_t)(kv0 + r) * H_ + ((kg ^ (r & 15)) * 8)],
                        (char*)&Ks[buf][0][0] + s * 4096 + tid * 16);
        }
#pragma unroll
        for (int s = 0; s < 4; ++s) {
            int h = s * 32 + vrow;
            GLOAD_LDS16(&VTb[(size_t)h * C_ + kv0 + ((vg ^ (h & 7)) * 8)],
                        (char*)&Vt[buf][0][0] + s * 4096 + tid * 16);
        }
    };

    STAGE(0, t0);

    for (int t = t0; t < t1; ++t) {
        const int cur = (t - t0) & 1;
        __syncthreads();
        if (t + 1 < t1) STAGE(cur ^ 1, t + 1);

        const int kv0 = t * 64;
        f32x4 s[4];
#pragma unroll
        for (int nf = 0; nf < 4; ++nf) {
            s[nf] = (f32x4){0.f, 0.f, 0.f, 0.f};
            const int rk = nf * 16 + lrow;
#pragma unroll
            for (int kf = 0; kf < 4; ++kf) {
                bf16x8 kb = *(const bf16x8*)&Ks[cur][rk][((kf * 4 + lq) ^ (rk & 15)) * 8];
                s[nf] = __builtin_amdgcn_mfma_f32_16x16x32_bf16(qf[kf], kb, s[nf], 0, 0, 0);
            }
        }
        bf16x8 vb[8][2];
#pragma unroll
        for (int nf = 0; nf < 8; ++nf) {
            const int h = nf * 16 + lrow;
#pragma unroll
            for (int kf2 = 0; kf2 < 2; ++kf2)
                vb[nf][kf2] = *(const bf16x8*)&Vt[cur][h][((kf2 * 4 + lq) ^ (h & 7)) * 8];
        }

        if (t == j) {
#pragma unroll
            for (int nf = 0; nf < 4; ++nf) {
                int key = kv0 + nf * 16 + lrow;
#pragma unroll
                for (int r = 0; r < 4; ++r)
                    if (key > qrow0 + r) s[nf][r] = -INFINITY;
            }
        }
        float mt[4] = {-INFINITY, -INFINITY, -INFINITY, -INFINITY};
#pragma unroll
        for (int nf = 0; nf < 4; ++nf)
#pragma unroll
            for (int r = 0; r < 4; ++r) mt[r] = fmaxf(mt[r], s[nf][r]);
#pragma unroll
        for (int r = 0; r < 4; ++r)
#pragma unroll
            for (int off = 1; off < 16; off <<= 1)
                mt[r] = fmaxf(mt[r], __shfl_xor(mt[r], off));

        float corr[4];
#pragma unroll
        for (int r = 0; r < 4; ++r) {
            float mn = fmaxf(m[r], mt[r]);
            corr[r] = __expf(m[r] - mn);
            m[r] = mn;
        }
        float ps[4] = {0.f, 0.f, 0.f, 0.f};
#pragma unroll
        for (int nf = 0; nf < 4; ++nf)
#pragma unroll
            for (int r = 0; r < 4; ++r) {
                float p = __expf(s[nf][r] - m[r]);
                ps[r] += p;
                Ps[wid][lq * 4 + r][nf * 16 + lrow] = f2bf(p);
            }
#pragma unroll
        for (int r = 0; r < 4; ++r) {
#pragma unroll
            for (int off = 1; off < 16; off <<= 1) ps[r] += __shfl_xor(ps[r], off);
            l[r] = l[r] * corr[r] + ps[r];
        }
#pragma unroll
        for (int nf = 0; nf < 8; ++nf)
#pragma unroll
            for (int r = 0; r < 4; ++r) o[nf][r] *= corr[r];

        bf16x8 pa[2];
#pragma unroll
        for (int kf2 = 0; kf2 < 2; ++kf2)
            pa[kf2] = *(const bf16x8*)&Ps[wid][lrow][kf2 * 32 + lk];
#pragma unroll
        for (int nf = 0; nf < 8; ++nf)
#pragma unroll
            for (int kf2 = 0; kf2 < 2; ++kf2)
                o[nf] = __builtin_amdgcn_mfma_f32_16x16x32_bf16(pa[kf2], vb[nf][kf2], o[nf], 0, 0, 0);
    }

    if (nch == 1) {       // j <= 3: single chunk, write normalized
#pragma unroll
        for (int nf = 0; nf < 8; ++nf) {
            int col = nf * 16 + lrow;
#pragma unroll
            for (int r = 0; r < 4; ++r)
                out[((size_t)b * C_ + qrow0 + r) * H_ + col] = o[nf][r] / l[r];
        }
    } else {              // partial: O (bf16, unnormalized) + m,l
        const int slot = b * SLOTS_B + rr;
        unsigned short* po = PO + (size_t)slot * 64 * 128;
        const int rl0 = wid * 16 + lq * 4;
#pragma unroll
        for (int nf = 0; nf < 8; ++nf) {
            int col = nf * 16 + lrow;
#pragma unroll
            for (int r = 0; r < 4; ++r)
                po[(size_t)(rl0 + r) * 128 + col] = f2bf(o[nf][r]);
        }
        if (lrow == 0) {
            float* ml = ML + (size_t)slot * 128;
#pragma unroll
            for (int r = 0; r < 4; ++r) {
                ml[rl0 + r] = m[r];
                ml[64 + rl0 + r] = l[r];
            }
        }
    }
}

// ---------------- combine partials for j >= 4 --------------------------------
__global__ __launch_bounds__(256) void combine_kernel(const unsigned short* __restrict__ PO,
                                                      const float* __restrict__ ML,
                                                      float* __restrict__ out) {
    const int j = blockIdx.x + 4;
    const int b = blockIdx.y;
    const int q = j >> 2, s = j & 3;
    const int Cj = j + 2 * q * (q - 1) + s * q;
    const int nch = q + 1;
    const int base = b * SLOTS_B + Cj;
    const int row = threadIdx.x >> 2;
    const int colg = (threadIdx.x & 3) * 32;

    float mstar = -INFINITY;
    for (int c = 0; c < nch; ++c)
        mstar = fmaxf(mstar, ML[(size_t)(base + c) * 128 + row]);

    float denom = 0.f;
    float acc[32];
#pragma unroll
    for (int i = 0; i < 32; ++i) acc[i] = 0.f;

    for (int c = 0; c < nch; ++c) {
        float mc = ML[(size_t)(base + c) * 128 + row];
        float lc = ML[(size_t)(base + c) * 128 + 64 + row];
        float w = __expf(mc - mstar);
        denom += w * lc;
        const unsigned short* p = PO + (size_t)(base + c) * 64 * 128 + (size_t)row * 128 + colg;
#pragma unroll
        for (int k = 0; k < 4; ++k) {
            bf16x8 v = *(const bf16x8*)&p[k * 8];
#pragma unroll
            for (int e = 0; e < 8; ++e)
                acc[k * 8 + e] += w * bf2f(((unsigned short*)&v)[e]);
        }
    }
    float inv = 1.f / denom;
    float* op = out + ((size_t)b * C_ + j * 64 + row) * H_ + colg;
#pragma unroll
    for (int k = 0; k < 8; ++k) {
        float4 st = {acc[k * 4] * inv, acc[k * 4 + 1] * inv, acc[k * 4 + 2] * inv, acc[k * 4 + 3] * inv};
        *(float4*)&op[k * 4] = st;
    }
}

extern "C" void kernel_launch(void* const* d_in, const int* in_sizes, int n_in,
                              void* d_out, int out_size, void* d_ws, size_t ws_size,
                              hipStream_t stream) {
    const float* x  = (const float*)d_in[0];
    const float* Wq = (const float*)d_in[1];
    const float* Wk = (const float*)d_in[2];
    const float* Wv = (const float*)d_in[3];
    float* out = (float*)d_out;

    // ws layout (~31.4 MB total):
    unsigned short* WT  = (unsigned short*)d_ws;                       // 768 KB
    unsigned short* QKV = WT + (size_t)3 * H_ * E_;                    // 12 MB (Q, K, V^T)
    unsigned short* PO  = QKV + (size_t)3 * M_ * H_;                   // 18 MB partial O
    float*          ML  = (float*)(PO + (size_t)8 * SLOTS_B * 64 * 128); // 576 KB m,l

    wt_kernel<<<dim3(H_ * E_ / 256, 3), 256, 0, stream>>>(Wq, Wk, Wv, WT);
    proj_kernel<<<dim3(M_ / 32), 256, 0, stream>>>(x, WT, QKV);
    attn_kernel<<<dim3(SLOTS_B, B_), 256, 0, stream>>>(QKV, PO, ML, out);
    combine_kernel<<<dim3(28, B_), 256, 0, stream>>>(PO, ML, out);
}